// Round 1
// baseline (1024.639 us; speedup 1.0000x reference)
//
#include <hip/hip_runtime.h>

// RobustAttention: blockwise (w=15) causal cosFormer linear attention.
// scores[l,j] = cos(th_l - th_j) * <relu(q_l), relu(k_j)>, j<=l
// out[l] = sum_j scores[l,j] * relu(v_j) / max(sum_j scores[l,j], 1e-6)
//
// R4: occupancy, not traffic, was the bottleneck (LDS 61,952 B capped us at
// 2 blocks/CU = 25% occupancy; k_lds had ZERO cross-group reuse — each tile
// was read by exactly one 16-lane group).
//  - LDS + __syncthreads removed entirely. Phase-1 reads relu(k) straight
//    from global: 16 lanes/group issue the same address -> single broadcast
//    transaction; every 64 B line is fully consumed across the c-loop (L1).
//  - Phase 1 restructured c-outer/j-inner: q streams through ONE float4 of
//    registers (was 64 VGPRs), keeping peak pressure in phase 2's vv[15]
//    so __launch_bounds__(256,4) holds without spills -> 16 waves/CU.
//  - Output stores are nontemporal: the 78.6 MB output stream no longer
//    evicts the L3-resident q/k/v inputs (inputs ~236 MB vs 256 MB L3).
//  - scores stay in registers; phase-2 fetches them with __shfl (unchanged).

namespace {

constexpr int W        = 15;            // block_size (rows per tile)
constexpr int CH       = 16;            // float4 per row (D=64)
constexpr int TILE4    = W * CH;        // 240 float4 per tile
constexpr int TPG      = 16;            // tiles per workgroup
constexpr int NTHREADS = 256;

typedef float f32x4_n __attribute__((ext_vector_type(4)));

__device__ __forceinline__ float4 relu4(float4 a) {
    return make_float4(fmaxf(a.x, 0.f), fmaxf(a.y, 0.f),
                       fmaxf(a.z, 0.f), fmaxf(a.w, 0.f));
}

__global__ __launch_bounds__(NTHREADS, 4)
void robust_attn_kernel(const float4* __restrict__ q4,
                        const float4* __restrict__ k4,
                        const float4* __restrict__ v4,
                        float4* __restrict__ o4,
                        int nblocks)
{
    const int tid  = threadIdx.x;
    const int lane = tid & 15;                 // row l (ph1) / d-chunk (ph2)
    const int t    = tid >> 4;                 // tile within WG
    const int g    = blockIdx.x * TPG + t;
    if (g >= nblocks) return;                  // no barrier -> early-out is safe

    // ---------- phase 1: normalized causal cos-weights, in registers -------
    float s[W];
#pragma unroll
    for (int j = 0; j < W; ++j) s[j] = 0.f;

    if (lane < W) {
        const int l = lane;
        const float4* __restrict__ qp = q4 + (size_t)g * TILE4 + l * CH;
        const float4* __restrict__ kp = k4 + (size_t)g * TILE4;

        // c-outer / j-inner: q lives in ONE float4; the 15 k loads per c are
        // independent (good MLP) and 16-lane-broadcast (cheap transactions).
#pragma unroll
        for (int c = 0; c < CH; ++c) {
            const float4 qc = relu4(qp[c]);
#pragma unroll
            for (int j = 0; j < W; ++j) {
                const float4 kk = relu4(kp[j * CH + c]);
                float acc = s[j];
                acc = fmaf(qc.x, kk.x, acc);
                acc = fmaf(qc.y, kk.y, acc);
                acc = fmaf(qc.z, kk.z, acc);
                acc = fmaf(qc.w, kk.w, acc);
                s[j] = acc;
            }
        }

        const float step = 1.57079632679489662f / (float)W;  // (pi/2)/15
        float denom = 0.f;
#pragma unroll
        for (int j = 0; j < W; ++j) {
            float wc = __cosf(step * (float)(l - j));
            float tv = (j <= l) ? s[j] * wc : 0.f;
            s[j] = tv;
            denom += tv;
        }
        const float inv = 1.f / fmaxf(denom, 1e-6f);
#pragma unroll
        for (int j = 0; j < W; ++j) s[j] *= inv;
    }

    // ---------- phase 2: out = S @ relu(v); weights via wave shuffle -------
    const float4* __restrict__ vp = v4 + (size_t)g * TILE4 + lane;
    float4* __restrict__ op       = o4 + (size_t)g * TILE4 + lane;

    float4 vv[W];
#pragma unroll
    for (int j = 0; j < W; ++j) vv[j] = relu4(vp[j * CH]);

    const int tbase = tid & 48;   // tile base lane within the wave
#pragma unroll
    for (int l = 0; l < W; ++l) {
        float ax = 0.f, ay = 0.f, az = 0.f, aw = 0.f;
#pragma unroll
        for (int j = 0; j <= l; ++j) {     // causal
            const float w = __shfl(s[j], tbase + l, 64);
            ax = fmaf(w, vv[j].x, ax);
            ay = fmaf(w, vv[j].y, ay);
            az = fmaf(w, vv[j].z, az);
            aw = fmaf(w, vv[j].w, aw);
        }
        // nontemporal: don't let the output stream evict L3-resident inputs
        f32x4_n val = {ax, ay, az, aw};
        __builtin_nontemporal_store(val, (f32x4_n*)(op + l * CH));
    }
}

}  // namespace

extern "C" void kernel_launch(void* const* d_in, const int* in_sizes, int n_in,
                              void* d_out, int out_size, void* d_ws, size_t ws_size,
                              hipStream_t stream) {
    const float4* q = (const float4*)d_in[0];
    const float4* k = (const float4*)d_in[1];
    const float4* v = (const float4*)d_in[2];
    float4* out = (float4*)d_out;

    const int total   = in_sizes[0];           // B*H*L*D
    const int nblocks = total / (W * CH * 4);  // 20480 for the bench shape
    const int wgs     = (nblocks + TPG - 1) / TPG;

    robust_attn_kernel<<<wgs, NTHREADS, 0, stream>>>(q, k, v, out, nblocks);
}

// Round 2
// 544.720 us; speedup vs baseline: 1.8810x; 1.8810x over previous
//
#include <hip/hip_runtime.h>

// RobustAttention: blockwise (w=15) causal cosFormer linear attention.
// scores[l,j] = cos(th_l - th_j) * <relu(q_l), relu(k_j)>, j<=l
// out[l] = sum_j scores[l,j] * relu(v_j) / max(sum_j scores[l,j], 1e-6)
//
// R5: R4's no-LDS rewrite spilled (VGPR 64 + 2.3 GB scratch traffic, 13x
// regression). Revert to R3's proven register structure (LDS k, j-outer/
// c-inner phase 1, ~108 VGPR no-spill) and fix occupancy the safe way:
//  - k staged in TWO row-halves (rows 0..7, then rows 8..14) through ONE
//    33,024 B buffer -> LDS/block halves (61,952 -> 33,024), blocks/CU
//    2 -> 4, waves/CU 8 -> 16 (VGPR<=128 via __launch_bounds__(256,4)).
//  - Dot loop split around the restage; 3 barriers total, overlapped
//    across the 4 resident blocks.
//  - Row-half staging is fully contiguous in global (2 KB runs/tile).
//  - Tile stride 129 float4 (= 4 banks skew) keeps the 4 groups of a wave
//    on disjoint banks for the broadcast ds_read_b128.
//  - NT output stores: the 78.6 MB output stream doesn't evict the
//    L3-resident inputs.

namespace {

constexpr int W        = 15;            // block_size (rows per tile)
constexpr int CH       = 16;            // float4 per row (D=64)
constexpr int TILE4    = W * CH;        // 240 float4 per tile
constexpr int TPG      = 16;            // tiles per workgroup
constexpr int NTHREADS = 256;
constexpr int ROWS_A   = 8;             // first staged half: rows 0..7
constexpr int HALF_A4  = ROWS_A * CH;           // 128 float4
constexpr int HALF_B4  = (W - ROWS_A) * CH;     // 112 float4 (rows 8..14)
constexpr int KSTRIDE4 = HALF_A4 + 1;           // 129: bank-skewed tile stride

typedef float f32x4_n __attribute__((ext_vector_type(4)));

__device__ __forceinline__ float4 relu4(float4 a) {
    return make_float4(fmaxf(a.x, 0.f), fmaxf(a.y, 0.f),
                       fmaxf(a.z, 0.f), fmaxf(a.w, 0.f));
}

__global__ __launch_bounds__(NTHREADS, 4)
void robust_attn_kernel(const float4* __restrict__ q4,
                        const float4* __restrict__ k4,
                        const float4* __restrict__ v4,
                        float4* __restrict__ o4,
                        int nblocks)
{
    __shared__ float4 k_lds[TPG * KSTRIDE4];   // 16*129*16 = 33,024 B

    const int tid  = threadIdx.x;
    const int lane = tid & 15;                 // row l (ph1) / d-chunk (ph2)
    const int t    = tid >> 4;                 // tile within WG
    const int g0   = blockIdx.x * TPG;
    const int g    = g0 + t;
    const bool active = (g < nblocks);
    const bool ph1    = active && (lane < W);

    // ---------- stage half A: relu(k) rows 0..7 of each tile ---------------
    {
        const size_t base = (size_t)g0 * TILE4;
#pragma unroll
        for (int r = 0; r < (TPG * HALF_A4) / NTHREADS; ++r) {   // 8 iters
            const int idx = tid + r * NTHREADS;
            const int tt  = idx >> 7;          // /128
            const int pos = idx & 127;
            float4 kk = make_float4(0.f, 0.f, 0.f, 0.f);
            if (g0 + tt < nblocks) kk = k4[base + tt * TILE4 + pos];
            k_lds[tt * KSTRIDE4 + pos] = relu4(kk);
        }
    }
    __syncthreads();

    // ---------- phase 1a: dots vs rows 0..7 (q resident in regs) -----------
    float s[W];
#pragma unroll
    for (int j = 0; j < W; ++j) s[j] = 0.f;

    float4 qr[CH];
    if (ph1) {
        const float4* __restrict__ qp = q4 + (size_t)g * TILE4 + lane * CH;
#pragma unroll
        for (int c = 0; c < CH; ++c) qr[c] = relu4(qp[c]);

        const float4* __restrict__ kl = &k_lds[t * KSTRIDE4];
#pragma unroll
        for (int j = 0; j < ROWS_A; ++j) {
            float acc = 0.f;
#pragma unroll
            for (int c = 0; c < CH; ++c) {
                const float4 kk = kl[j * CH + c];
                acc = fmaf(qr[c].x, kk.x, acc);
                acc = fmaf(qr[c].y, kk.y, acc);
                acc = fmaf(qr[c].z, kk.z, acc);
                acc = fmaf(qr[c].w, kk.w, acc);
            }
            s[j] = acc;
        }
    }
    __syncthreads();   // everyone done reading half A

    // ---------- stage half B: relu(k) rows 8..14 (same buffer) -------------
    {
        const size_t base = (size_t)g0 * TILE4 + HALF_A4;
#pragma unroll
        for (int r = 0; r < (TPG * HALF_B4) / NTHREADS; ++r) {   // 7 iters
            const int idx = tid + r * NTHREADS;
            const int tt  = idx / HALF_B4;     // /112: magic-mul
            const int pos = idx - tt * HALF_B4;
            float4 kk = make_float4(0.f, 0.f, 0.f, 0.f);
            if (g0 + tt < nblocks) kk = k4[base + tt * TILE4 + pos];
            k_lds[tt * KSTRIDE4 + pos] = relu4(kk);
        }
    }
    __syncthreads();

    // ---------- phase 1b: dots vs rows 8..14, cos-weight, normalize --------
    if (ph1) {
        const int l = lane;
        const float4* __restrict__ kl = &k_lds[t * KSTRIDE4];
#pragma unroll
        for (int j = ROWS_A; j < W; ++j) {
            float acc = 0.f;
#pragma unroll
            for (int c = 0; c < CH; ++c) {
                const float4 kk = kl[(j - ROWS_A) * CH + c];
                acc = fmaf(qr[c].x, kk.x, acc);
                acc = fmaf(qr[c].y, kk.y, acc);
                acc = fmaf(qr[c].z, kk.z, acc);
                acc = fmaf(qr[c].w, kk.w, acc);
            }
            s[j] = acc;
        }

        const float step = 1.57079632679489662f / (float)W;  // (pi/2)/15
        float denom = 0.f;
#pragma unroll
        for (int j = 0; j < W; ++j) {
            float wc = __cosf(step * (float)(l - j));
            float tv = (j <= l) ? s[j] * wc : 0.f;
            s[j] = tv;
            denom += tv;
        }
        const float inv = 1.f / fmaxf(denom, 1e-6f);
#pragma unroll
        for (int j = 0; j < W; ++j) s[j] *= inv;
    }

    // ---------- phase 2: out = S @ relu(v); weights via wave shuffle -------
    if (active) {
        const float4* __restrict__ vp = v4 + (size_t)g * TILE4 + lane;
        float4* __restrict__ op       = o4 + (size_t)g * TILE4 + lane;

        float4 vv[W];
#pragma unroll
        for (int j = 0; j < W; ++j) vv[j] = relu4(vp[j * CH]);

        const int tbase = tid & 48;   // tile base lane within the wave
#pragma unroll
        for (int l = 0; l < W; ++l) {
            float ax = 0.f, ay = 0.f, az = 0.f, aw = 0.f;
#pragma unroll
            for (int j = 0; j <= l; ++j) {     // causal
                const float w = __shfl(s[j], tbase + l, 64);
                ax = fmaf(w, vv[j].x, ax);
                ay = fmaf(w, vv[j].y, ay);
                az = fmaf(w, vv[j].z, az);
                aw = fmaf(w, vv[j].w, aw);
            }
            // nontemporal: output stream must not evict L3-resident inputs
            f32x4_n val = {ax, ay, az, aw};
            __builtin_nontemporal_store(val, (f32x4_n*)(op + l * CH));
        }
    }
}

}  // namespace

extern "C" void kernel_launch(void* const* d_in, const int* in_sizes, int n_in,
                              void* d_out, int out_size, void* d_ws, size_t ws_size,
                              hipStream_t stream) {
    const float4* q = (const float4*)d_in[0];
    const float4* k = (const float4*)d_in[1];
    const float4* v = (const float4*)d_in[2];
    float4* out = (float4*)d_out;

    const int total   = in_sizes[0];           // B*H*L*D
    const int nblocks = total / (W * CH * 4);  // 20480 for the bench shape
    const int wgs     = (nblocks + TPG - 1) / TPG;

    robust_attn_kernel<<<wgs, NTHREADS, 0, stream>>>(q, k, v, out, nblocks);
}

// Round 3
// 76.379 us; speedup vs baseline: 13.4153x; 7.1318x over previous
//
#include <hip/hip_runtime.h>

// RobustAttention: blockwise (w=15) causal cosFormer linear attention.
// scores[l,j] = cos(th_l - th_j) * <relu(q_l), relu(k_j)>, j<=l
// out[l] = sum_j scores[l,j] * relu(v_j) / max(sum_j scores[l,j], 1e-6)
//
// R6: R5's occupancy fix (LDS 62K -> 33K via two-half k staging) WORKED
// (occupancy 17.8 -> 39.7%) but __launch_bounds__(256,4) capped the
// allocator at 128 VGPR < ~140 live -> spill (VGPR tier 64, 1.6 GB
// scratch traffic). Same root cause as R4's regression.
// Fix: keep the halved LDS, revert to R3's proven __launch_bounds__(256,2).
// The bound is only an allocator constraint; R3's identical register
// structure lands at 108 VGPR, and 108 <= 128 means the HARDWARE grants
// 4 waves/EU anyway. With LDS at 33,024 B (4 blocks/CU) we get the full
// 16 waves/CU without forcing spills.
//  - k staged in TWO row-halves (rows 0..7, then 8..14) through ONE
//    33,024 B buffer; dot loop split around the restage; 3 barriers.
//  - Tile stride 129 float4 keeps broadcast ds_reads bank-skewed.
//  - NT output stores: output stream doesn't evict L3-resident inputs.

namespace {

constexpr int W        = 15;            // block_size (rows per tile)
constexpr int CH       = 16;            // float4 per row (D=64)
constexpr int TILE4    = W * CH;        // 240 float4 per tile
constexpr int TPG      = 16;            // tiles per workgroup
constexpr int NTHREADS = 256;
constexpr int ROWS_A   = 8;             // first staged half: rows 0..7
constexpr int HALF_A4  = ROWS_A * CH;           // 128 float4
constexpr int HALF_B4  = (W - ROWS_A) * CH;     // 112 float4 (rows 8..14)
constexpr int KSTRIDE4 = HALF_A4 + 1;           // 129: bank-skewed tile stride

typedef float f32x4_n __attribute__((ext_vector_type(4)));

__device__ __forceinline__ float4 relu4(float4 a) {
    return make_float4(fmaxf(a.x, 0.f), fmaxf(a.y, 0.f),
                       fmaxf(a.z, 0.f), fmaxf(a.w, 0.f));
}

__global__ __launch_bounds__(NTHREADS, 2)
void robust_attn_kernel(const float4* __restrict__ q4,
                        const float4* __restrict__ k4,
                        const float4* __restrict__ v4,
                        float4* __restrict__ o4,
                        int nblocks)
{
    __shared__ float4 k_lds[TPG * KSTRIDE4];   // 16*129*16 = 33,024 B

    const int tid  = threadIdx.x;
    const int lane = tid & 15;                 // row l (ph1) / d-chunk (ph2)
    const int t    = tid >> 4;                 // tile within WG
    const int g0   = blockIdx.x * TPG;
    const int g    = g0 + t;
    const bool active = (g < nblocks);
    const bool ph1    = active && (lane < W);

    // ---------- stage half A: relu(k) rows 0..7 of each tile ---------------
    {
        const size_t base = (size_t)g0 * TILE4;
#pragma unroll
        for (int r = 0; r < (TPG * HALF_A4) / NTHREADS; ++r) {   // 8 iters
            const int idx = tid + r * NTHREADS;
            const int tt  = idx >> 7;          // /128
            const int pos = idx & 127;
            float4 kk = make_float4(0.f, 0.f, 0.f, 0.f);
            if (g0 + tt < nblocks) kk = k4[base + tt * TILE4 + pos];
            k_lds[tt * KSTRIDE4 + pos] = relu4(kk);
        }
    }
    __syncthreads();

    // ---------- phase 1a: dots vs rows 0..7 (q resident in regs) -----------
    float s[W];
#pragma unroll
    for (int j = 0; j < W; ++j) s[j] = 0.f;

    float4 qr[CH];
    if (ph1) {
        const float4* __restrict__ qp = q4 + (size_t)g * TILE4 + lane * CH;
#pragma unroll
        for (int c = 0; c < CH; ++c) qr[c] = relu4(qp[c]);

        const float4* __restrict__ kl = &k_lds[t * KSTRIDE4];
#pragma unroll
        for (int j = 0; j < ROWS_A; ++j) {
            float acc = 0.f;
#pragma unroll
            for (int c = 0; c < CH; ++c) {
                const float4 kk = kl[j * CH + c];
                acc = fmaf(qr[c].x, kk.x, acc);
                acc = fmaf(qr[c].y, kk.y, acc);
                acc = fmaf(qr[c].z, kk.z, acc);
                acc = fmaf(qr[c].w, kk.w, acc);
            }
            s[j] = acc;
        }
    }
    __syncthreads();   // everyone done reading half A

    // ---------- stage half B: relu(k) rows 8..14 (same buffer) -------------
    {
        const size_t base = (size_t)g0 * TILE4 + HALF_A4;
#pragma unroll
        for (int r = 0; r < (TPG * HALF_B4) / NTHREADS; ++r) {   // 7 iters
            const int idx = tid + r * NTHREADS;
            const int tt  = idx / HALF_B4;     // /112: magic-mul
            const int pos = idx - tt * HALF_B4;
            float4 kk = make_float4(0.f, 0.f, 0.f, 0.f);
            if (g0 + tt < nblocks) kk = k4[base + tt * TILE4 + pos];
            k_lds[tt * KSTRIDE4 + pos] = relu4(kk);
        }
    }
    __syncthreads();

    // ---------- phase 1b: dots vs rows 8..14, cos-weight, normalize --------
    if (ph1) {
        const int l = lane;
        const float4* __restrict__ kl = &k_lds[t * KSTRIDE4];
#pragma unroll
        for (int j = ROWS_A; j < W; ++j) {
            float acc = 0.f;
#pragma unroll
            for (int c = 0; c < CH; ++c) {
                const float4 kk = kl[(j - ROWS_A) * CH + c];
                acc = fmaf(qr[c].x, kk.x, acc);
                acc = fmaf(qr[c].y, kk.y, acc);
                acc = fmaf(qr[c].z, kk.z, acc);
                acc = fmaf(qr[c].w, kk.w, acc);
            }
            s[j] = acc;
        }

        const float step = 1.57079632679489662f / (float)W;  // (pi/2)/15
        float denom = 0.f;
#pragma unroll
        for (int j = 0; j < W; ++j) {
            float wc = __cosf(step * (float)(l - j));
            float tv = (j <= l) ? s[j] * wc : 0.f;
            s[j] = tv;
            denom += tv;
        }
        const float inv = 1.f / fmaxf(denom, 1e-6f);
#pragma unroll
        for (int j = 0; j < W; ++j) s[j] *= inv;
    }

    // ---------- phase 2: out = S @ relu(v); weights via wave shuffle -------
    if (active) {
        const float4* __restrict__ vp = v4 + (size_t)g * TILE4 + lane;
        float4* __restrict__ op       = o4 + (size_t)g * TILE4 + lane;

        float4 vv[W];
#pragma unroll
        for (int j = 0; j < W; ++j) vv[j] = relu4(vp[j * CH]);

        const int tbase = tid & 48;   // tile base lane within the wave
#pragma unroll
        for (int l = 0; l < W; ++l) {
            float ax = 0.f, ay = 0.f, az = 0.f, aw = 0.f;
#pragma unroll
            for (int j = 0; j <= l; ++j) {     // causal
                const float w = __shfl(s[j], tbase + l, 64);
                ax = fmaf(w, vv[j].x, ax);
                ay = fmaf(w, vv[j].y, ay);
                az = fmaf(w, vv[j].z, az);
                aw = fmaf(w, vv[j].w, aw);
            }
            // nontemporal: output stream must not evict L3-resident inputs
            f32x4_n val = {ax, ay, az, aw};
            __builtin_nontemporal_store(val, (f32x4_n*)(op + l * CH));
        }
    }
}

}  // namespace

extern "C" void kernel_launch(void* const* d_in, const int* in_sizes, int n_in,
                              void* d_out, int out_size, void* d_ws, size_t ws_size,
                              hipStream_t stream) {
    const float4* q = (const float4*)d_in[0];
    const float4* k = (const float4*)d_in[1];
    const float4* v = (const float4*)d_in[2];
    float4* out = (float4*)d_out;

    const int total   = in_sizes[0];           // B*H*L*D
    const int nblocks = total / (W * CH * 4);  // 20480 for the bench shape
    const int wgs     = (nblocks + TPG - 1) / TPG;

    robust_attn_kernel<<<wgs, NTHREADS, 0, stream>>>(q, k, v, out, nblocks);
}